// Round 1
// baseline (517.897 us; speedup 1.0000x reference)
//
#include <hip/hip_runtime.h>

// ---------------------------------------------------------------------------
// RPN head on gfx950: x --conv3x3(512->256)+relu--> h1 --conv3x3(256->256)+relu
//   --> h2 --1x1 heads (cls 18 / reg 36)--> softmax pairs --> out (B,H,W,9,6)
// R3: conv3x3 rebuilt as a pipelined 256x256 macro-tile implicit GEMM:
//   - 8 waves (512 thr), wave tile 128x64, acc[4][2] of 32x32x16 bf16 MFMA
//     (768 B LDS-read per MFMA vs 1024 before -> below LDS BW ceiling)
//   - BK=32, double-buffered LDS (2 x 73.7 KB), global_load_lds(16B) DMA
//   - counted s_waitcnt vmcnt(9) across raw s_barriers: next tile's loads
//     stay in flight through compute (breaks the 37% MfmaUtil barrier-drain
//     ceiling of the old 2-barrier reg-staging loop)
//   - XOR swizzle seg^=(row>>1)&3 applied on the GLOBAL source at stage time
//     and on ds_read addresses (linear LDS dest required by global_load_lds)
// ---------------------------------------------------------------------------

typedef float f32x4  __attribute__((ext_vector_type(4)));
typedef float f32x16 __attribute__((ext_vector_type(16)));
typedef short bf16x8 __attribute__((ext_vector_type(8)));   // 8 bf16 = 4 VGPRs

union U16x8 { uint4 v; unsigned short s[8]; };

__device__ __forceinline__ unsigned short f2bf(float f) {
  union { float f; unsigned int u; } v; v.f = f;
  unsigned int r = v.u + 0x7FFFu + ((v.u >> 16) & 1u);   // RNE
  return (unsigned short)(r >> 16);
}

#define GLOAD_LDS16(G, L)                                        \
  __builtin_amdgcn_global_load_lds(                              \
      (const __attribute__((address_space(1))) void*)(G),        \
      (__attribute__((address_space(3))) void*)(L), 16, 0, 0)

// ---- transpose + fp32->bf16: src[z][K][N] -> dst[z][N][K] ------------------
__global__ __launch_bounds__(256) void transpose_cvt(
    const float* __restrict__ src, unsigned short* __restrict__ dst,
    int K, int N) {
  __shared__ float t[32][33];
  const int tx = threadIdx.x, ty = threadIdx.y;     // 32 x 8
  const int k0 = blockIdx.x * 32, n0 = blockIdx.y * 32;
  const float* s = src + (size_t)blockIdx.z * K * N;
  unsigned short* d = dst + (size_t)blockIdx.z * N * K;
#pragma unroll
  for (int r = 0; r < 32; r += 8) {
    int k = k0 + ty + r, n = n0 + tx;
    t[ty + r][tx] = (k < K && n < N) ? s[(size_t)k * N + n] : 0.f;
  }
  __syncthreads();
#pragma unroll
  for (int r = 0; r < 32; r += 8) {
    int n = n0 + ty + r, k = k0 + tx;
    if (n < N && k < K) d[(size_t)n * K + k] = f2bf(t[tx][ty + r]);
  }
}

// ---- x (f32 NHWC) -> x_pad (bf16, [4][130][130][512], zero halo) -----------
__global__ __launch_bounds__(256) void convert_x(
    const float* __restrict__ x, unsigned short* __restrict__ xp) {
  int idx = blockIdx.x * 256 + threadIdx.x;       // 4*130*130*64 exactly
  int g = idx & 63;                                // 8-channel group
  int cell = idx >> 6;
  int xpix = cell % 130;
  int t = cell / 130;
  int ypix = t % 130;
  int b = t / 130;
  U16x8 u;
  if (xpix == 0 || xpix == 129 || ypix == 0 || ypix == 129) {
    u.v = make_uint4(0u, 0u, 0u, 0u);
  } else {
    const float* sp = x + ((size_t)((b * 128 + ypix - 1) * 128) + (xpix - 1)) * 512 + g * 8;
    float4 a = *(const float4*)sp;
    float4 c = *(const float4*)(sp + 4);
    u.s[0] = f2bf(a.x); u.s[1] = f2bf(a.y); u.s[2] = f2bf(a.z); u.s[3] = f2bf(a.w);
    u.s[4] = f2bf(c.x); u.s[5] = f2bf(c.y); u.s[6] = f2bf(c.z); u.s[7] = f2bf(c.w);
  }
  *(uint4*)(xp + (size_t)cell * 512 + g * 8) = u.v;
}

// ---- zero the halo of h1_pad ([4][130][130][256]) --------------------------
__global__ __launch_bounds__(256) void zero_h1_borders(unsigned short* __restrict__ h1p) {
  int idx = blockIdx.x * 256 + threadIdx.x;       // 4*130*130*32 exactly
  int g = idx & 31;
  int cell = idx >> 5;
  int xpix = cell % 130;
  int t = cell / 130;
  int ypix = t % 130;
  if (xpix == 0 || xpix == 129 || ypix == 0 || ypix == 129)
    *(uint4*)(h1p + (size_t)cell * 256 + g * 8) = make_uint4(0u, 0u, 0u, 0u);
}

// ---- 3x3 conv, pipelined implicit GEMM, bf16 MFMA 32x32x16 -----------------
// Ap:  [4][130][130][CIN] bf16 (zero halo).  WT: [9][256][CIN] bf16 (B^T).
// Block tile: 256 output pixels (2 image rows x 128 px) x 256 cout.
// Grid: 256 blocks (b*64 + row-pair), 512 threads = 8 waves (2M x 4N),
// wave tile 128x64.  K-loop: t = (dy, ci0) with BK=32, dx-merged A rows.
// LDS per buffer: A [2 rows][192 px][4 segs] 24.6 KB (px>129 staged but never
// read), B [3 dx][256 co][4 segs] 49.2 KB.  Double-buffered = 147 456 B.
// Stage = 9 global_load_lds(16B) per wave; s_waitcnt vmcnt(9) keeps the next
// tile's DMA in flight across the barrier (counted-vmcnt pipeline).
// Swizzle: LDS seg holds global seg ^ ((row>>1)&3)  (row = px for A, co for B)
// -> 8 consecutive lanes of a ds_read_b128 hit 8 distinct 16B slots.
template<int CIN, int MODE>
__global__ __launch_bounds__(512, 2) void conv3x3(
    const unsigned short* __restrict__ Ap,
    const unsigned short* __restrict__ WT,
    const float* __restrict__ bias,
    unsigned short* __restrict__ out) {
  constexpr int NCI    = CIN / 32;
  constexpr int LOGNCI = (NCI == 16) ? 4 : 3;
  constexpr int NT     = 3 * NCI;
  constexpr int A_BYTES = 2 * 192 * 4 * 16;       // 24 576
  constexpr int B_BYTES = 3 * 256 * 4 * 16;       // 49 152
  constexpr int BUF     = A_BYTES + B_BYTES;      // 73 728
  __shared__ __align__(16) unsigned char smem[2 * BUF];

  const int tid  = threadIdx.x;
  const int wave = tid >> 6, lane = tid & 63;
  const int l31 = lane & 31, hi = lane >> 5;
  const int wm = wave >> 2, wn = wave & 3;        // 2M x 4N wave grid
  const int b = blockIdx.x >> 6;
  const int y0 = (blockIdx.x & 63) * 2;
  const int brow = b * 130 + y0;                  // input row at dy=0, bufrow 0

  // ---- per-thread staging decode (constant across iterations) -------------
  int a_go[3], a_ld[3];
#pragma unroll
  for (int i = 0; i < 3; ++i) {
    int s = (wave * 3 + i) * 64 + lane;           // 0..1535
    int br = (s >= 768) ? 1 : 0;
    int r = s - br * 768;
    int px = r >> 2, sl = r & 3;
    a_go[i] = (br * 130 + px) * CIN + ((sl ^ ((px >> 1) & 3)) * 8);
    a_ld[i] = (wave * 3 + i) * 1024;
  }
  int b_go[6], b_ld[6];
#pragma unroll
  for (int i = 0; i < 6; ++i) {
    int s = (wave * 6 + i) * 64 + lane;           // 0..3071
    int dxs = s >> 10, r = s & 1023;
    int co = r >> 2, sl = r & 3;
    b_go[i] = (dxs * 256 + co) * CIN + ((sl ^ ((co >> 1) & 3)) * 8);
    b_ld[i] = A_BYTES + (wave * 6 + i) * 1024;
  }

  // bias loads issued (and retired) before the pipeline's vmcnt counting
  const float bb0 = bias[wn * 64 + l31];
  const float bb1 = bias[wn * 64 + 32 + l31];

  f32x16 acc[4][2] = {};
  const int bswz = (l31 >> 1) & 3;

  auto stage = [&](int tile) {
    const int dy  = tile >> LOGNCI;
    const int ci0 = (tile & (NCI - 1)) << 5;
    unsigned char* sb = smem + (size_t)(tile & 1) * BUF;
    const unsigned short* Ab = Ap + (size_t)(brow + dy) * 130 * CIN + ci0;
#pragma unroll
    for (int i = 0; i < 3; ++i)
      GLOAD_LDS16(Ab + a_go[i], sb + a_ld[i]);
    const unsigned short* Bb = WT + (size_t)dy * 3 * 256 * CIN + ci0;
#pragma unroll
    for (int i = 0; i < 6; ++i)
      GLOAD_LDS16(Bb + b_go[i], sb + b_ld[i]);
  };

  auto compute = [&](int t) {
    const unsigned char* sb = smem + (size_t)(t & 1) * BUF;
#pragma unroll
    for (int dx = 0; dx < 3; ++dx) {
      const int aswz  = ((l31 + dx) >> 1) & 3;
      const int abase = wm * 12288 + (l31 + dx) * 64;
      const int bbase = A_BYTES + dx * 16384 + wn * 4096 + l31 * 64;
#pragma unroll
      for (int ks = 0; ks < 2; ++ks) {
        const int q = ks * 2 + hi;
        bf16x8 af[4], bfr[2];
        const int ab = abase + ((q ^ aswz) * 16);
#pragma unroll
        for (int i = 0; i < 4; ++i)
          af[i] = *(const bf16x8*)(sb + ab + i * 2048);
        const int bby = bbase + ((q ^ bswz) * 16);
#pragma unroll
        for (int j = 0; j < 2; ++j)
          bfr[j] = *(const bf16x8*)(sb + bby + j * 2048);
#pragma unroll
        for (int i = 0; i < 4; ++i)
#pragma unroll
          for (int j = 0; j < 2; ++j)
            acc[i][j] = __builtin_amdgcn_mfma_f32_32x32x16_bf16(af[i], bfr[j], acc[i][j], 0, 0, 0);
      }
    }
  };

  stage(0);
#pragma unroll 2
  for (int t = 0; t < NT - 1; ++t) {
    stage(t + 1);                                  // 9 DMA loads, async
    asm volatile("s_waitcnt vmcnt(9)" ::: "memory"); // tile t resident (own wave)
    __builtin_amdgcn_s_barrier();                  // tile t resident (all waves)
    __builtin_amdgcn_sched_barrier(0);
    compute(t);
    __builtin_amdgcn_sched_barrier(0);
    __builtin_amdgcn_s_barrier();                  // all waves done reading buf t
  }
  asm volatile("s_waitcnt vmcnt(0)" ::: "memory");
  __builtin_amdgcn_s_barrier();
  __builtin_amdgcn_sched_barrier(0);
  compute(NT - 1);

  // epilogue: 32x32 C/D layout: col = lane&31, row = (reg&3)+8*(reg>>2)+4*hi
#pragma unroll
  for (int i = 0; i < 4; ++i) {
#pragma unroll
    for (int j = 0; j < 2; ++j) {
      const int n = wn * 64 + j * 32 + l31;
      const float bb = j ? bb1 : bb0;
#pragma unroll
      for (int reg = 0; reg < 16; ++reg) {
        int px = i * 32 + (reg & 3) + 8 * (reg >> 2) + 4 * hi;
        float v = fmaxf(acc[i][j][reg] + bb, 0.f);
        size_t off;
        if (MODE == 0)
          off = ((size_t)(brow + wm + 1) * 130 + (px + 1)) * 256 + n;
        else
          off = ((size_t)(b * 128 + y0 + wm) * 128 + px) * 256 + n;
        out[off] = f2bf(v);
      }
    }
  }
}

// ---- heads: h2[65536][256] x WhT[54(pad 64)][256] + bias, softmax pairs ----
__global__ __launch_bounds__(256) void heads_kernel(
    const unsigned short* __restrict__ h2,
    const unsigned short* __restrict__ WhT,
    const float* __restrict__ br, const float* __restrict__ bc,
    float* __restrict__ out) {
  __shared__ __align__(16) unsigned short As[64][264];
  const int tid = threadIdx.x;
  const int wave = tid >> 6, lane = tid & 63;
  const int quad = lane >> 4, l16 = lane & 15;
  const int pix0 = blockIdx.x * 64;
#pragma unroll
  for (int r = 0; r < 8; ++r) {
    int s = r * 256 + tid;
    int row = s >> 5, seg = s & 31;                  // 64 rows x 32 x 16B
    *(uint4*)&As[row][seg * 8] =
        *(const uint4*)(h2 + (size_t)(pix0 + row) * 256 + seg * 8);
  }
  __syncthreads();
  f32x4 acc[4] = {};
#pragma unroll
  for (int ks = 0; ks < 8; ++ks) {
    bf16x8 af = *(const bf16x8*)&As[wave * 16 + l16][ks * 32 + quad * 8];
#pragma unroll
    for (int j = 0; j < 4; ++j) {
      bf16x8 bfr = *(const bf16x8*)(WhT + (size_t)(j * 16 + l16) * 256 + ks * 32 + quad * 8);
      acc[j] = __builtin_amdgcn_mfma_f32_16x16x32_bf16(af, bfr, acc[j], 0, 0, 0);
    }
  }
#pragma unroll
  for (int j = 0; j < 4; ++j) {
    int n = j * 16 + l16;                            // head channel (cls 0-17, reg 18-53)
    float bias = 0.f;
    if (n < 18) bias = bc[n];
    else if (n < 54) bias = br[n - 18];
#pragma unroll
    for (int r = 0; r < 4; ++r) {
      int p = pix0 + wave * 16 + quad * 4 + r;       // pixel
      float v = acc[j][r] + bias;
      float partner = __shfl_xor(v, 1);              // cls pair (even,odd lanes)
      if (n < 18) {
        float mx = fmaxf(v, partner);
        float e0 = __expf(v - mx), e1 = __expf(partner - mx);
        int a = n >> 1, sl = n & 1;
        out[(size_t)p * 54 + a * 6 + sl] = e0 / (e0 + e1);
      } else if (n < 54) {
        int rr = n - 18, a = rr >> 2, sl = (rr & 3) + 2;
        out[(size_t)p * 54 + a * 6 + sl] = v;
      }
    }
  }
}

// ---------------------------------------------------------------------------
extern "C" void kernel_launch(void* const* d_in, const int* in_sizes, int n_in,
                              void* d_out, int out_size, void* d_ws, size_t ws_size,
                              hipStream_t stream) {
  const float* x  = (const float*)d_in[0];
  const float* W1 = (const float*)d_in[1];
  const float* b1 = (const float*)d_in[2];
  const float* W2 = (const float*)d_in[3];
  const float* b2 = (const float*)d_in[4];
  const float* Wr = (const float*)d_in[5];
  const float* br = (const float*)d_in[6];
  const float* Wc = (const float*)d_in[7];
  const float* bc = (const float*)d_in[8];
  float* out = (float*)d_out;

  // workspace carve-up (bytes).  NOTE: conv3x3 A-staging over-reads up to
  // ~64 KB past x_pad / ~32 KB past h1_pad (uniform-DMA row padding to 192 px);
  // those reads land in the NEXT buffer and are never consumed by MFMA, so no
  // extra padding is required as long as the order below is kept.
  constexpr size_t XPAD_B  = 4ull * 130 * 130 * 512 * 2;   //  69,222,400
  constexpr size_t H1PAD_B = 4ull * 130 * 130 * 256 * 2;   //  34,611,200
  constexpr size_t H2_B    = 4ull * 128 * 128 * 256 * 2;   //  33,554,432
  constexpr size_t W1T_B   = 9ull * 256 * 512 * 2;         //   2,359,296
  constexpr size_t W2T_B   = 9ull * 256 * 256 * 2;         //   1,179,648
  char* ws = (char*)d_ws;
  unsigned short* x_pad  = (unsigned short*)(ws);
  unsigned short* h1_pad = (unsigned short*)(ws + XPAD_B);
  unsigned short* h2     = (unsigned short*)(ws + XPAD_B + H1PAD_B);
  unsigned short* W1T    = (unsigned short*)(ws + XPAD_B + H1PAD_B + H2_B);
  unsigned short* W2T    = (unsigned short*)(ws + XPAD_B + H1PAD_B + H2_B + W1T_B);
  unsigned short* WhT    = (unsigned short*)(ws + XPAD_B + H1PAD_B + H2_B + W1T_B + W2T_B);

  // zero the padded head-weight block (rows 54..63 are read by MFMA)
  hipMemsetAsync(WhT, 0, 64ull * 256 * 2, stream);
  // weight repacks (B^T, bf16)
  transpose_cvt<<<dim3(16, 8, 9), dim3(32, 8), 0, stream>>>(W1, W1T, 512, 256);
  transpose_cvt<<<dim3(8, 8, 9),  dim3(32, 8), 0, stream>>>(W2, W2T, 256, 256);
  transpose_cvt<<<dim3(8, 1, 1),  dim3(32, 8), 0, stream>>>(Wc, WhT, 256, 18);
  transpose_cvt<<<dim3(8, 2, 1),  dim3(32, 8), 0, stream>>>(Wr, WhT + 18 * 256, 256, 36);
  // input pad+convert, h1 halo zero
  convert_x<<<16900, 256, 0, stream>>>(x, x_pad);
  zero_h1_borders<<<8450, 256, 0, stream>>>(h1_pad);
  // conv1: 512ci -> h1_pad (interior) ; conv2: 256ci -> h2 flat
  conv3x3<512, 0><<<256, 512, 0, stream>>>(x_pad, W1T, b1, h1_pad);
  conv3x3<256, 1><<<256, 512, 0, stream>>>(h1_pad, W2T, b2, h2);
  // 1x1 heads + softmax + interleave
  heads_kernel<<<1024, 256, 0, stream>>>(h2, WhT, br, bc, out);
}

// Round 2
// 481.472 us; speedup vs baseline: 1.0757x; 1.0757x over previous
//
#include <hip/hip_runtime.h>

// ---------------------------------------------------------------------------
// RPN head on gfx950: x --conv3x3(512->256)+relu--> h1 --conv3x3(256->256)+relu
//   --> h2 --1x1 heads (cls 18 / reg 36)--> softmax pairs --> out (B,H,W,9,6)
// R4: conv3x3 converted from 2-phase (stage|compute) to the proven 8-phase-
// style schedule (T3+T4+T5): each BK=32 tile is 3 sub-phases (one per dx tap)
//   { 12 ds_read_b128 ; [dx0: 9 DMA next tile] ; [dx2: vmcnt(0) -> publish]
//     s_barrier ; lgkmcnt(0) ; setprio(1) ; 16 MFMA ; setprio(0) ; s_barrier }
// Reads of phase p+1 overlap the MFMA drain of phase p (staggered lgkm
// release across waves) -> per-phase time ~= max(LDS drain, MFMA drain)
// instead of the sum that pinned R2/R3 at 37% MfmaUtil.
// ---------------------------------------------------------------------------

typedef float f32x4  __attribute__((ext_vector_type(4)));
typedef float f32x16 __attribute__((ext_vector_type(16)));
typedef short bf16x8 __attribute__((ext_vector_type(8)));   // 8 bf16 = 4 VGPRs

union U16x8 { uint4 v; unsigned short s[8]; };

__device__ __forceinline__ unsigned short f2bf(float f) {
  union { float f; unsigned int u; } v; v.f = f;
  unsigned int r = v.u + 0x7FFFu + ((v.u >> 16) & 1u);   // RNE
  return (unsigned short)(r >> 16);
}

#define GLOAD_LDS16(G, L)                                        \
  __builtin_amdgcn_global_load_lds(                              \
      (const __attribute__((address_space(1))) void*)(G),        \
      (__attribute__((address_space(3))) void*)(L), 16, 0, 0)

// ---- transpose + fp32->bf16: src[z][K][N] -> dst[z][N][K] ------------------
__global__ __launch_bounds__(256) void transpose_cvt(
    const float* __restrict__ src, unsigned short* __restrict__ dst,
    int K, int N) {
  __shared__ float t[32][33];
  const int tx = threadIdx.x, ty = threadIdx.y;     // 32 x 8
  const int k0 = blockIdx.x * 32, n0 = blockIdx.y * 32;
  const float* s = src + (size_t)blockIdx.z * K * N;
  unsigned short* d = dst + (size_t)blockIdx.z * N * K;
#pragma unroll
  for (int r = 0; r < 32; r += 8) {
    int k = k0 + ty + r, n = n0 + tx;
    t[ty + r][tx] = (k < K && n < N) ? s[(size_t)k * N + n] : 0.f;
  }
  __syncthreads();
#pragma unroll
  for (int r = 0; r < 32; r += 8) {
    int n = n0 + ty + r, k = k0 + tx;
    if (n < N && k < K) d[(size_t)n * K + k] = f2bf(t[tx][ty + r]);
  }
}

// ---- x (f32 NHWC) -> x_pad (bf16, [4][130][130][512], zero halo) -----------
__global__ __launch_bounds__(256) void convert_x(
    const float* __restrict__ x, unsigned short* __restrict__ xp) {
  int idx = blockIdx.x * 256 + threadIdx.x;       // 4*130*130*64 exactly
  int g = idx & 63;                                // 8-channel group
  int cell = idx >> 6;
  int xpix = cell % 130;
  int t = cell / 130;
  int ypix = t % 130;
  int b = t / 130;
  U16x8 u;
  if (xpix == 0 || xpix == 129 || ypix == 0 || ypix == 129) {
    u.v = make_uint4(0u, 0u, 0u, 0u);
  } else {
    const float* sp = x + ((size_t)((b * 128 + ypix - 1) * 128) + (xpix - 1)) * 512 + g * 8;
    float4 a = *(const float4*)sp;
    float4 c = *(const float4*)(sp + 4);
    u.s[0] = f2bf(a.x); u.s[1] = f2bf(a.y); u.s[2] = f2bf(a.z); u.s[3] = f2bf(a.w);
    u.s[4] = f2bf(c.x); u.s[5] = f2bf(c.y); u.s[6] = f2bf(c.z); u.s[7] = f2bf(c.w);
  }
  *(uint4*)(xp + (size_t)cell * 512 + g * 8) = u.v;
}

// ---- zero the halo of h1_pad ([4][130][130][256]) --------------------------
__global__ __launch_bounds__(256) void zero_h1_borders(unsigned short* __restrict__ h1p) {
  int idx = blockIdx.x * 256 + threadIdx.x;       // 4*130*130*32 exactly
  int g = idx & 31;
  int cell = idx >> 5;
  int xpix = cell % 130;
  int t = cell / 130;
  int ypix = t % 130;
  if (xpix == 0 || xpix == 129 || ypix == 0 || ypix == 129)
    *(uint4*)(h1p + (size_t)cell * 256 + g * 8) = make_uint4(0u, 0u, 0u, 0u);
}

// ---- 3x3 conv, phase-split implicit GEMM, bf16 MFMA 32x32x16 ---------------
// Ap:  [4][130][130][CIN] bf16 (zero halo).  WT: [9][256][CIN] bf16 (B^T).
// Block tile: 256 output pixels (2 rows x 128 px) x 256 cout; 8 waves 2Mx4N,
// wave tile 128x64, acc[4][2].  K-loop: tile t = (dy, ci0), BK=32.
// Per tile, 3 phases (dx = 0,1,2); per phase/wave: 12 ds_read_b128 + 16 MFMA.
// Staging: 9 global_load_lds(16B)/wave for tile t+1 issued at phase (t,0)
// (WAR-safe after (t-1,2) closing barrier); own-wave vmcnt(0) at (t,2) before
// the pre-MFMA barrier, which thus publishes buf t+1 block-wide.  The drain
// covers loads issued ~2 phases (~2000 cyc) earlier -> no stall.
// Swizzle (both-sides): LDS slot = global slot ^ ((row>>1)&3); consecutive
// lanes hit distinct 16B bank-quarters on ds_read_b128.
template<int CIN, int MODE>
__global__ __launch_bounds__(512, 2) void conv3x3(
    const unsigned short* __restrict__ Ap,
    const unsigned short* __restrict__ WT,
    const float* __restrict__ bias,
    unsigned short* __restrict__ out) {
  constexpr int NCI    = CIN / 32;
  constexpr int LOGNCI = (NCI == 16) ? 4 : 3;
  constexpr int NT     = 3 * NCI;
  constexpr int A_BYTES = 2 * 192 * 4 * 16;       // 24 576
  constexpr int B_BYTES = 3 * 256 * 4 * 16;       // 49 152
  constexpr int BUF     = A_BYTES + B_BYTES;      // 73 728
  __shared__ __align__(16) unsigned char smem[2 * BUF];

  const int tid  = threadIdx.x;
  const int wave = tid >> 6, lane = tid & 63;
  const int l31 = lane & 31, hi = lane >> 5;
  const int wm = wave >> 2, wn = wave & 3;        // 2M x 4N wave grid
  const int b = blockIdx.x >> 6;
  const int y0 = (blockIdx.x & 63) * 2;
  const int brow = b * 130 + y0;                  // input row at dy=0

  // ---- per-thread staging decode (constant across iterations) -------------
  int a_go[3], a_ld[3];
#pragma unroll
  for (int i = 0; i < 3; ++i) {
    int s = (wave * 3 + i) * 64 + lane;           // 0..1535
    int br = (s >= 768) ? 1 : 0;
    int r = s - br * 768;
    int px = r >> 2, sl = r & 3;
    a_go[i] = (br * 130 + px) * CIN + ((sl ^ ((px >> 1) & 3)) * 8);
    a_ld[i] = (wave * 3 + i) * 1024;
  }
  int b_go[6], b_ld[6];
#pragma unroll
  for (int i = 0; i < 6; ++i) {
    int s = (wave * 6 + i) * 64 + lane;           // 0..3071
    int dxs = s >> 10, r = s & 1023;
    int co = r >> 2, sl = r & 3;
    b_go[i] = (dxs * 256 + co) * CIN + ((sl ^ ((co >> 1) & 3)) * 8);
    b_ld[i] = A_BYTES + (wave * 6 + i) * 1024;
  }

  // bias loads issued (and retired) before the pipeline's vmcnt counting
  const float bb0 = bias[wn * 64 + l31];
  const float bb1 = bias[wn * 64 + 32 + l31];

  f32x16 acc[4][2] = {};
  const int bswz = (l31 >> 1) & 3;

  auto stage = [&](int tile) {
    const int dy  = tile >> LOGNCI;
    const int ci0 = (tile & (NCI - 1)) << 5;
    unsigned char* sb = smem + (size_t)(tile & 1) * BUF;
    const unsigned short* Ab = Ap + (size_t)(brow + dy) * 130 * CIN + ci0;
#pragma unroll
    for (int i = 0; i < 3; ++i)
      GLOAD_LDS16(Ab + a_go[i], sb + a_ld[i]);
    const unsigned short* Bb = WT + (size_t)dy * 3 * 256 * CIN + ci0;
#pragma unroll
    for (int i = 0; i < 6; ++i)
      GLOAD_LDS16(Bb + b_go[i], sb + b_ld[i]);
  };

  // prologue: stage tile 0, publish
  stage(0);
  asm volatile("s_waitcnt vmcnt(0)" ::: "memory");
  __builtin_amdgcn_s_barrier();

#pragma unroll 2
  for (int t = 0; t < NT; ++t) {
    const unsigned char* sb = smem + (size_t)(t & 1) * BUF;
#pragma unroll
    for (int dx = 0; dx < 3; ++dx) {
      // ---- issue this phase's fragment reads (buf t, published earlier) ---
      const int aswz  = ((l31 + dx) >> 1) & 3;
      const int abase = wm * 12288 + (l31 + dx) * 64;
      const int bbase = A_BYTES + dx * 16384 + wn * 4096 + l31 * 64;
      bf16x8 af[2][4], bfr[2][2];
#pragma unroll
      for (int ks = 0; ks < 2; ++ks) {
        const int q  = ks * 2 + hi;
        const int ab  = abase + ((q ^ aswz) * 16);
        const int bby = bbase + ((q ^ bswz) * 16);
#pragma unroll
        for (int i = 0; i < 4; ++i)
          af[ks][i] = *(const bf16x8*)(sb + ab + i * 2048);
#pragma unroll
        for (int j = 0; j < 2; ++j)
          bfr[ks][j] = *(const bf16x8*)(sb + bby + j * 2048);
      }
      // ---- staging schedule for tile t+1 ----------------------------------
      if (dx == 0 && t + 1 < NT) stage(t + 1);     // 9 DMAs -> buf^1 (WAR-safe)
      if (dx == 2 && t + 1 < NT)                   // issued 2 phases ago: no stall
        asm volatile("s_waitcnt vmcnt(0)" ::: "memory");
      __builtin_amdgcn_sched_barrier(0);
      __builtin_amdgcn_s_barrier();                // (t,2): publishes buf t+1
      asm volatile("s_waitcnt lgkmcnt(0)" ::: "memory");
      __builtin_amdgcn_sched_barrier(0);
      __builtin_amdgcn_s_setprio(1);
#pragma unroll
      for (int ks = 0; ks < 2; ++ks)
#pragma unroll
        for (int i = 0; i < 4; ++i)
#pragma unroll
          for (int j = 0; j < 2; ++j)
            acc[i][j] = __builtin_amdgcn_mfma_f32_32x32x16_bf16(
                af[ks][i], bfr[ks][j], acc[i][j], 0, 0, 0);
      __builtin_amdgcn_s_setprio(0);
      __builtin_amdgcn_sched_barrier(0);
      __builtin_amdgcn_s_barrier();                // phase close
    }
  }

  // epilogue: 32x32 C/D layout: col = lane&31, row = (reg&3)+8*(reg>>2)+4*hi
#pragma unroll
  for (int i = 0; i < 4; ++i) {
#pragma unroll
    for (int j = 0; j < 2; ++j) {
      const int n = wn * 64 + j * 32 + l31;
      const float bb = j ? bb1 : bb0;
#pragma unroll
      for (int reg = 0; reg < 16; ++reg) {
        int px = i * 32 + (reg & 3) + 8 * (reg >> 2) + 4 * hi;
        float v = fmaxf(acc[i][j][reg] + bb, 0.f);
        size_t off;
        if (MODE == 0)
          off = ((size_t)(brow + wm + 1) * 130 + (px + 1)) * 256 + n;
        else
          off = ((size_t)(b * 128 + y0 + wm) * 128 + px) * 256 + n;
        out[off] = f2bf(v);
      }
    }
  }
}

// ---- heads: h2[65536][256] x WhT[54(pad 64)][256] + bias, softmax pairs ----
__global__ __launch_bounds__(256) void heads_kernel(
    const unsigned short* __restrict__ h2,
    const unsigned short* __restrict__ WhT,
    const float* __restrict__ br, const float* __restrict__ bc,
    float* __restrict__ out) {
  __shared__ __align__(16) unsigned short As[64][264];
  const int tid = threadIdx.x;
  const int wave = tid >> 6, lane = tid & 63;
  const int quad = lane >> 4, l16 = lane & 15;
  const int pix0 = blockIdx.x * 64;
#pragma unroll
  for (int r = 0; r < 8; ++r) {
    int s = r * 256 + tid;
    int row = s >> 5, seg = s & 31;                  // 64 rows x 32 x 16B
    *(uint4*)&As[row][seg * 8] =
        *(const uint4*)(h2 + (size_t)(pix0 + row) * 256 + seg * 8);
  }
  __syncthreads();
  f32x4 acc[4] = {};
#pragma unroll
  for (int ks = 0; ks < 8; ++ks) {
    bf16x8 af = *(const bf16x8*)&As[wave * 16 + l16][ks * 32 + quad * 8];
#pragma unroll
    for (int j = 0; j < 4; ++j) {
      bf16x8 bfr = *(const bf16x8*)(WhT + (size_t)(j * 16 + l16) * 256 + ks * 32 + quad * 8);
      acc[j] = __builtin_amdgcn_mfma_f32_16x16x32_bf16(af, bfr, acc[j], 0, 0, 0);
    }
  }
#pragma unroll
  for (int j = 0; j < 4; ++j) {
    int n = j * 16 + l16;                            // head channel (cls 0-17, reg 18-53)
    float bias = 0.f;
    if (n < 18) bias = bc[n];
    else if (n < 54) bias = br[n - 18];
#pragma unroll
    for (int r = 0; r < 4; ++r) {
      int p = pix0 + wave * 16 + quad * 4 + r;       // pixel
      float v = acc[j][r] + bias;
      float partner = __shfl_xor(v, 1);              // cls pair (even,odd lanes)
      if (n < 18) {
        float mx = fmaxf(v, partner);
        float e0 = __expf(v - mx), e1 = __expf(partner - mx);
        int a = n >> 1, sl = n & 1;
        out[(size_t)p * 54 + a * 6 + sl] = e0 / (e0 + e1);
      } else if (n < 54) {
        int rr = n - 18, a = rr >> 2, sl = (rr & 3) + 2;
        out[(size_t)p * 54 + a * 6 + sl] = v;
      }
    }
  }
}

// ---------------------------------------------------------------------------
extern "C" void kernel_launch(void* const* d_in, const int* in_sizes, int n_in,
                              void* d_out, int out_size, void* d_ws, size_t ws_size,
                              hipStream_t stream) {
  const float* x  = (const float*)d_in[0];
  const float* W1 = (const float*)d_in[1];
  const float* b1 = (const float*)d_in[2];
  const float* W2 = (const float*)d_in[3];
  const float* b2 = (const float*)d_in[4];
  const float* Wr = (const float*)d_in[5];
  const float* br = (const float*)d_in[6];
  const float* Wc = (const float*)d_in[7];
  const float* bc = (const float*)d_in[8];
  float* out = (float*)d_out;

  // workspace carve-up (bytes).  NOTE: conv3x3 A-staging over-reads up to
  // ~64 KB past x_pad / ~32 KB past h1_pad (uniform-DMA row padding to 192 px);
  // those reads land in the NEXT buffer and are never consumed by MFMA, so no
  // extra padding is required as long as the order below is kept.
  constexpr size_t XPAD_B  = 4ull * 130 * 130 * 512 * 2;   //  69,222,400
  constexpr size_t H1PAD_B = 4ull * 130 * 130 * 256 * 2;   //  34,611,200
  constexpr size_t H2_B    = 4ull * 128 * 128 * 256 * 2;   //  33,554,432
  constexpr size_t W1T_B   = 9ull * 256 * 512 * 2;         //   2,359,296
  constexpr size_t W2T_B   = 9ull * 256 * 256 * 2;         //   1,179,648
  char* ws = (char*)d_ws;
  unsigned short* x_pad  = (unsigned short*)(ws);
  unsigned short* h1_pad = (unsigned short*)(ws + XPAD_B);
  unsigned short* h2     = (unsigned short*)(ws + XPAD_B + H1PAD_B);
  unsigned short* W1T    = (unsigned short*)(ws + XPAD_B + H1PAD_B + H2_B);
  unsigned short* W2T    = (unsigned short*)(ws + XPAD_B + H1PAD_B + H2_B + W1T_B);
  unsigned short* WhT    = (unsigned short*)(ws + XPAD_B + H1PAD_B + H2_B + W1T_B + W2T_B);

  // zero the padded head-weight block (rows 54..63 are read by MFMA)
  hipMemsetAsync(WhT, 0, 64ull * 256 * 2, stream);
  // weight repacks (B^T, bf16)
  transpose_cvt<<<dim3(16, 8, 9), dim3(32, 8), 0, stream>>>(W1, W1T, 512, 256);
  transpose_cvt<<<dim3(8, 8, 9),  dim3(32, 8), 0, stream>>>(W2, W2T, 256, 256);
  transpose_cvt<<<dim3(8, 1, 1),  dim3(32, 8), 0, stream>>>(Wc, WhT, 256, 18);
  transpose_cvt<<<dim3(8, 2, 1),  dim3(32, 8), 0, stream>>>(Wr, WhT + 18 * 256, 256, 36);
  // input pad+convert, h1 halo zero
  convert_x<<<16900, 256, 0, stream>>>(x, x_pad);
  zero_h1_borders<<<8450, 256, 0, stream>>>(h1_pad);
  // conv1: 512ci -> h1_pad (interior) ; conv2: 256ci -> h2 flat
  conv3x3<512, 0><<<256, 512, 0, stream>>>(x_pad, W1T, b1, h1_pad);
  conv3x3<256, 1><<<256, 512, 0, stream>>>(h1_pad, W2T, b2, h2);
  // 1x1 heads + softmax + interleave
  heads_kernel<<<1024, 256, 0, stream>>>(h2, WhT, br, bc, out);
}